// Round 7
// baseline (6544.144 us; speedup 1.0000x reference)
//
#include <hip/hip_runtime.h>

// Decoder: 2-layer LSTM, B=1024, IN=256, H=512, OUT=256, T2=128 (hardcoded).
// PERSISTENT kernel, 256 blocks x 512 thr, 1 block/CU (~64KB LDS).
// Round-10: BARRIER-FREE register pipeline. 16 batch-groups of 64 rows,
// 16 j-blocks, XCD-LOCAL (2 groups per XCD), dataflow handshakes (r6 scheme).
//   - Waves remapped to (gate, K-half): B-weight fragments become DISJOINT
//     per-wave slices, A fragments a per-wave K-half -> both load straight
//     to REGISTERS (plain per-lane loads), 3-deep rotating buffer, NO LDS
//     staging and NO s_barrier in the granule loop. Waves self-pace; the
//     lockstep that bounded r5-r6 (~3200cyc/granule vs ~300 of work) is gone.
//   - Loads pinned by asm volatile("" ::: "memory") fences (r3's prefetch
//     was sunk by the compiler precisely for lack of these); exact waits
//     are compiler-inserted per first use.
//   - K-half partials summed through a 64KB LDS arena at the epilogue
//     (one __syncthreads), which also hosts the proj stage (aliased).
//   - A-duplication across the 4 same-K-half waves is served by L1 (8KB
//     granules, no buffer_inv within a phase); B traffic stays 1x.
//   - K-order flipped (cell0 [h0|z], cell1 [h1|h0]) so the first granules
//     read provably-ready t-1 data -> prologue issues BEFORE the handshake.
//   - c-state + biases in VGPRs; activations through XCD-local L2 (plain
//     st/ld + buffer_inv at handshakes).

typedef __attribute__((ext_vector_type(8))) __bf16 bf16x8;
typedef __attribute__((ext_vector_type(16))) float f32x16;
typedef unsigned long long ull;

__device__ __forceinline__ f32x16 mfma_bf16(bf16x8 a, bf16x8 b, f32x16 c) {
  return __builtin_amdgcn_mfma_f32_32x32x16_bf16(a, b, c, 0, 0, 0);
}

__device__ __forceinline__ short f2bf(float f) {  // RNE fp32->bf16
  unsigned u = __float_as_uint(f);
  u += 0x7fffu + ((u >> 16) & 1u);
  return (short)(u >> 16);
}

__device__ __forceinline__ float sigm(float x) { return 1.0f / (1.0f + __expf(-x)); }
__device__ __forceinline__ float tanh_fast(float x) { return 2.0f / (1.0f + __expf(-2.0f * x)) - 1.0f; }

__device__ __forceinline__ f32x16 zero16() {
  f32x16 z;
#pragma unroll
  for (int i = 0; i < 16; ++i) z[i] = 0.0f;
  return z;
}

// proj A-tile LDS layout: row m (0..63) at stride 132 shorts (padded).
#define AT_STRIDE 132

// ---------------------------------------------------------------------------
// prep: swizzle weights into MFMA B-frag order (granule-contiguous), FLIPPED
// K-order; sum biases; init bf16 states; init ready-counters (cnt[z1]=8,
// cnt[h0_0]=16, cnt[h1_0]=16 — prep is the t=-1 producer).
// flags: per group g: flags[g*256 + type*32], type 0=z[0],1=z[1],2=h0[0],
// 3=h0[1],4=h1[0],5=h1[1]. XCD ctrs at 8192+x*32.
// ---------------------------------------------------------------------------
__global__ __launch_bounds__(256) void prep_kernel(
    const float* __restrict__ z0, const float* __restrict__ h0in,
    const float* __restrict__ Wih0, const float* __restrict__ Whh0,
    const float* __restrict__ bih0, const float* __restrict__ bhh0,
    const float* __restrict__ Wih1, const float* __restrict__ Whh1,
    const float* __restrict__ bih1, const float* __restrict__ bhh1,
    const float* __restrict__ fcW, const float* __restrict__ linW,
    short* __restrict__ wsw0, short* __restrict__ wsw1,
    short* __restrict__ fcWsw, short* __restrict__ linWsw,
    float* __restrict__ bias0, float* __restrict__ bias1,
    short* __restrict__ zb1, short* __restrict__ h0b0, short* __restrict__ h1b0,
    int* __restrict__ flags)
{
  int idx = blockIdx.x * 256 + threadIdx.x;
  if (idx < 1572864) {  // wsw0 [j16][s48][g4][l64][8]; K=768 = [h0 512 | z 256]
    int jj = idx & 7, l = (idx >> 3) & 63, gg = (idx >> 9) & 3;
    int rest = idx >> 11;           // j*48 + s
    int s = rest % 48, b = rest / 48;
    int row = gg * 512 + b * 32 + (l & 31);
    int k = s * 16 + (l >> 5) * 8 + jj;
    wsw0[idx] = f2bf(k < 512 ? Whh0[row * 512 + k] : Wih0[row * 256 + (k - 512)]);
    return;
  }
  idx -= 1572864;
  if (idx < 2097152) {  // wsw1 [j16][s64][g4][l64][8]; K=1024 = [h1 512 | h0 512]
    int jj = idx & 7, l = (idx >> 3) & 63, gg = (idx >> 9) & 3;
    int rest = idx >> 11;           // j*64 + s
    int s = rest & 63, b = rest >> 6;
    int row = gg * 512 + b * 32 + (l & 31);
    int k = s * 16 + (l >> 5) * 8 + jj;
    wsw1[idx] = f2bf(k < 512 ? Whh1[row * 512 + k] : Wih1[row * 512 + (k - 512)]);
    return;
  }
  idx -= 2097152;
  if (idx < 131072) {  // fcWsw [jz8][s32][l64][8]
    int jj = idx & 7, l = (idx >> 3) & 63, s = (idx >> 9) & 31, jz = idx >> 14;
    int col = jz * 32 + (l & 31);
    int k = s * 16 + (l >> 5) * 8 + jj;
    fcWsw[idx] = f2bf(fcW[col * 512 + k]);
    return;
  }
  idx -= 131072;
  if (idx < 65536) {  // linWsw [jo8][s16][l64][8]
    int jj = idx & 7, l = (idx >> 3) & 63, s = (idx >> 9) & 15, jo = idx >> 13;
    int col = jo * 32 + (l & 31);
    int k = s * 16 + (l >> 5) * 8 + jj;
    linWsw[idx] = f2bf(linW[col * 256 + k]);
    return;
  }
  idx -= 65536;
  if (idx < 2048) { bias0[idx] = bih0[idx] + bhh0[idx]; return; }
  idx -= 2048;
  if (idx < 2048) { bias1[idx] = bih1[idx] + bhh1[idx]; return; }
  idx -= 2048;
  if (idx < 262144) { zb1[idx] = f2bf(z0[idx]); return; }
  idx -= 262144;
  if (idx < 524288) { h0b0[idx] = f2bf(h0in[idx]); return; }
  idx -= 524288;
  if (idx < 524288) { h1b0[idx] = f2bf(h0in[524288 + idx]); return; }
  idx -= 524288;
  if (idx < 8448) {  // ready-counters + xcd ctrs
    int v = 0;
    if (idx < 8192) {
      int off = idx & 255;
      if (off == 32) v = 8;                       // cnt_z[1] (prep wrote zb1)
      else if (off == 64 || off == 128) v = 16;   // cnt_h0[0], cnt_h1[0]
    }
    flags[idx] = v;
    return;
  }
}

// ---------------------------------------------------------------------------
// Dataflow sync: producers add 1 (after vmcnt drain); consumers poll to a
// monotone target, then buffer_inv (per-CU L1 invalidate; XCD L2 stays warm).
// ---------------------------------------------------------------------------
__device__ __forceinline__ void wait1(int* c0, int v0) {
  __syncthreads();
  if (threadIdx.x == 0) {
    while (__hip_atomic_load(c0, __ATOMIC_RELAXED, __HIP_MEMORY_SCOPE_AGENT) < v0)
      __builtin_amdgcn_s_sleep(2);
    asm volatile("buffer_inv" ::: "memory");
  }
  __syncthreads();
}

__device__ __forceinline__ void wait2(int* c0, int v0, int* c1, int v1) {
  __syncthreads();
  if (threadIdx.x == 0) {
    while (__hip_atomic_load(c0, __ATOMIC_RELAXED, __HIP_MEMORY_SCOPE_AGENT) < v0 ||
           __hip_atomic_load(c1, __ATOMIC_RELAXED, __HIP_MEMORY_SCOPE_AGENT) < v1)
      __builtin_amdgcn_s_sleep(2);
    asm volatile("buffer_inv" ::: "memory");
  }
  __syncthreads();
}

__device__ __forceinline__ void produce(int* c) {
  asm volatile("s_waitcnt vmcnt(0)" ::: "memory");
  __syncthreads();
  if (threadIdx.x == 0)
    __hip_atomic_fetch_add(c, 1, __ATOMIC_RELAXED, __HIP_MEMORY_SCOPE_AGENT);
}

// ---------------------------------------------------------------------------
// Barrier-free LSTM cell phase (M=64, K granule = 64, 512 thr, 8 waves).
// Wave = (gq = gate, ks = K-half). Per granule per wave: 4 A-frags (2 sl x
// 2 mh) + 2 B-frags -> 4 MFMAs into acc[mh] (K-half partials). 3-deep
// rotating register buffer; loads pinned by memory-clobber fences; exact
// waits compiler-inserted. Epilogue sums ks-partials via the 64KB arena.
// ---------------------------------------------------------------------------
template <int NG, int TAG, bool PREWAIT>
__device__ __forceinline__ void cell_phase_reg(
    float* gbig,
    const short* __restrict__ srcA, int ldA,
    const short* __restrict__ srcB, int ldB,
    const short* __restrict__ wgl,
    const float (&br)[4][4],
    float* cr, short* hout, int row0, int j0,
    int* c0, int v0, int* c1, int v1)
{
  const int t = threadIdx.x;
  const int w = t >> 6, l = t & 63;
  const int gq = w & 3, ks = w >> 2;   // wave = (gate quadrant, K-half)
  const int ln = l & 31, kh = l >> 5;

  uint4 aR[3][2][2];  // [slot][sl][mh]
  uint4 bR[3][2];     // [slot][sl]
  f32x16 acc0 = zero16(), acc1 = zero16();

  auto issue = [&](int g, int slot) {
    const short* src; int ld, gk;
    if (g < TAG) { src = srcA; ld = ldA; gk = g * 64; }
    else         { src = srcB; ld = ldB; gk = (g - TAG) * 64; }
#pragma unroll
    for (int sl = 0; sl < 2; ++sl) {
      const int ko = gk + (ks * 2 + sl) * 16 + kh * 8;
#pragma unroll
      for (int mh = 0; mh < 2; ++mh)
        aR[slot][sl][mh] =
            *(const uint4*)&src[(size_t)(row0 + mh * 32 + ln) * ld + ko];
      bR[slot][sl] = *(const uint4*)
          &wgl[(size_t)g * 8192 + (((ks * 2 + sl) * 4 + gq) * 64 + l) * 8];
    }
  };

  if (PREWAIT) {           // prologue sources provably ready (t-1 data)
    issue(0, 0); issue(1, 1); issue(2, 2);
    asm volatile("" ::: "memory");
    wait2(c0, v0, c1, v1);
  } else {
    wait2(c0, v0, c1, v1);
    issue(0, 0); issue(1, 1); issue(2, 2);
  }

#pragma unroll
  for (int g = 0; g < NG; ++g) {
    asm volatile("" ::: "memory");   // loads stay on their side of the fence
    const int slot = g % 3;
#pragma unroll
    for (int sl = 0; sl < 2; ++sl) {
      bf16x8 b, a0, a1;
      __builtin_memcpy(&b,  &bR[slot][sl],    16);
      __builtin_memcpy(&a0, &aR[slot][sl][0], 16);
      __builtin_memcpy(&a1, &aR[slot][sl][1], 16);
      acc0 = mfma_bf16(a0, b, acc0);
      acc1 = mfma_bf16(a1, b, acc1);
    }
    asm volatile("" ::: "memory");
    if (g + 3 < NG) issue(g + 3, slot);   // refills the slot just consumed
  }

  // partial C: col = lane&31, row = (r&3)+8*(r>>2)+4*kh (+32 for mh=1)
#pragma unroll
  for (int r = 0; r < 16; ++r) {
    int mloc = (r & 3) + 8 * (r >> 2) + 4 * kh;
    gbig[ks * 8192 + (gq * 64 + mloc) * 32 + ln] = acc0[r];
    gbig[ks * 8192 + (gq * 64 + mloc + 32) * 32 + ln] = acc1[r];
  }
  __syncthreads();
  const int m = t >> 3, nb = (t & 7) * 4;  // m 0..63, nb 0..28
  short hh[4];
#pragma unroll
  for (int u = 0; u < 4; ++u) {
    int n = nb + u;
    float gi = gbig[(0 * 64 + m) * 32 + n] + gbig[8192 + (0 * 64 + m) * 32 + n] + br[0][u];
    float gf = gbig[(1 * 64 + m) * 32 + n] + gbig[8192 + (1 * 64 + m) * 32 + n] + br[1][u];
    float gg = gbig[(2 * 64 + m) * 32 + n] + gbig[8192 + (2 * 64 + m) * 32 + n] + br[2][u];
    float go = gbig[(3 * 64 + m) * 32 + n] + gbig[8192 + (3 * 64 + m) * 32 + n] + br[3][u];
    float cn = sigm(gf) * cr[u] + sigm(gi) * tanh_fast(gg);
    cr[u] = cn;
    hh[u] = f2bf(sigm(go) * tanh_fast(cn));
  }
  ull hv; __builtin_memcpy(&hv, hh, 8);
  *(ull*)&hout[(size_t)(row0 + m) * 512 + j0 + nb] = hv;  // plain: same-XCD L2
}

// ---------------------------------------------------------------------------
// Projection partials (fc or lin), M=64, 512 thr: waves (kq = w>>1, mh = w&1).
// A-stage loads AND B-fragments prefetched into VGPRs upfront.
// ---------------------------------------------------------------------------
template <int NQ>
__device__ __forceinline__ void proj_partials(
    short* At0, float* gbuf,
    const short* __restrict__ src, int ld,
    const short* __restrict__ wblk, int row0)
{
  const int t = threadIdx.x;
  const int w = t >> 6, l = t & 63;
  const int kq = w >> 1, mh = w & 1;
  const int ln = l & 31, kh = l >> 5;
  const int sks = t & 15, sm = t >> 4;   // staging: ks 0..15, m 0..31 (+32)
  f32x16 acc = zero16();
  uint4 pre[NQ][2];
  bf16x8 bfr[NQ][2];
#pragma unroll
  for (int q = 0; q < NQ; ++q) {
#pragma unroll
    for (int i = 0; i < 2; ++i)
      pre[q][i] = *(const uint4*)&src[(row0 + sm + 32 * i) * ld + q * 128 + sks * 8];
#pragma unroll
    for (int sl = 0; sl < 2; ++sl)
      bfr[q][sl] = *(const bf16x8*)&wblk[((q * 8 + kq * 2 + sl) * 64 + l) * 8];
  }
#pragma unroll
  for (int q = 0; q < NQ; ++q) {
    __syncthreads();
#pragma unroll
    for (int i = 0; i < 2; ++i)
      *(uint4*)&At0[(sm + 32 * i) * AT_STRIDE + sks * 8] = pre[q][i];
    __syncthreads();
#pragma unroll
    for (int sl = 0; sl < 2; ++sl) {
      int s16 = kq * 2 + sl;
      bf16x8 a = *(const bf16x8*)&At0[(mh * 32 + ln) * AT_STRIDE + (s16 * 2 + kh) * 8];
      acc = mfma_bf16(a, bfr[q][sl], acc);
    }
  }
  __syncthreads();
#pragma unroll
  for (int r = 0; r < 16; ++r) {
    int mloc = (r & 3) + 8 * (r >> 2) + 4 * kh + mh * 32;
    gbuf[(kq * 64 + mloc) * 32 + ln] = acc[r];
  }
  __syncthreads();
}

__global__ __launch_bounds__(512, 1) void decoder_persist(
    const short* __restrict__ wsw0, const short* __restrict__ wsw1,
    const short* __restrict__ fcWsw, const short* __restrict__ linWsw,
    const float* __restrict__ bias0, const float* __restrict__ bias1,
    const float* __restrict__ fcb, const float* __restrict__ linb,
    const float* __restrict__ c0in,
    short* h0x, short* h0y, short* h1x, short* h1y, short* zx, short* zy,
    int* flags, float* __restrict__ outp)
{
  __shared__ __align__(16) float gbig[16384];  // 64KB arena: cell partials /
  __shared__ int sgj[2];                       // proj Atp+gbufp (aliased)
  short* Atp = (short*)gbig;                   // 16896 B
  float* gbufp = (float*)((char*)gbig + 16896);// 32 KB

  // --- self-assignment: physical XCD id -> (group, j) slot ---
  if (threadIdx.x == 0) {
    unsigned xcc;
    asm volatile("s_getreg_b32 %0, hwreg(HW_REG_XCC_ID, 0, 32)" : "=s"(xcc));
    xcc &= 7u;
    int slot = __hip_atomic_fetch_add(&flags[8192 + (int)xcc * 32], 1,
                                      __ATOMIC_RELAXED, __HIP_MEMORY_SCOPE_AGENT);
    slot &= 31;                           // hardening: wrong-answer > hang
    sgj[0] = (int)xcc * 2 + (slot >> 4);  // group: 2 per XCD
    sgj[1] = slot & 15;                   // j-tile within group
  }
  __syncthreads();
  const int g = sgj[0], j = sgj[1];
  const int row0 = g * 64, j0 = j * 32;
  int* cnt = &flags[g * 256];             // 6 counters, one cacheline each
#define CZ(i)  (cnt + (0 + (i)) * 32)
#define CH0(i) (cnt + (2 + (i)) * 32)
#define CH1(i) (cnt + (4 + (i)) * 32)

  // --- c-state + loop-invariant biases in registers for the whole run ---
  float c0r[4], c1r[4], b0r[4][4], b1r[4][4], fbr[4];
  {
    const int m = threadIdx.x >> 3, nb = (threadIdx.x & 7) * 4;
#pragma unroll
    for (int u = 0; u < 4; ++u) {
      c0r[u] = c0in[(size_t)(row0 + m) * 512 + j0 + nb + u];
      c1r[u] = c0in[524288 + (size_t)(row0 + m) * 512 + j0 + nb + u];
      int jn = j0 + nb + u;
#pragma unroll
      for (int gt = 0; gt < 4; ++gt) {
        b0r[gt][u] = bias0[gt * 512 + jn];
        b1r[gt][u] = bias1[gt * 512 + jn];
      }
      fbr[u] = (j < 8) ? fcb[j * 32 + nb + u] : linb[(j - 8) * 32 + nb + u];
    }
  }

  short* h0buf[2] = {h0x, h0y};
  short* h1buf[2] = {h1x, h1y};
  short* zbuf[2] = {zx, zy};
  const short* wg0 = wsw0 + j * 98304;
  const short* wg1 = wsw1 + j * 131072;
  const short* wpj = (j < 8) ? (fcWsw + j * 16384) : (linWsw + (j - 8) * 8192);

#pragma unroll 1
  for (int t = 0; t < 128; ++t) {
    const int p = t & 1;
    const int half = (t >> 1) + 1;        // completed write-rounds, t-1 parity
    const int full = (t + 3) >> 1;        // incl. this step
    // P1: cell0  (K = [h0(t-1) 512 | z(t-1) 256]); prologue pre-wait
    // (h0(t-1) provably ready: full(t-1)==half(t); CZ is the real gate).
    cell_phase_reg<12, 8, true>(gbig, h0buf[p], 512, zbuf[p ^ 1], 256,
                                wg0, b0r, c0r, h0buf[p ^ 1], row0, j0,
                                CZ(p ^ 1), 8 * half, CH0(p), 16 * half);
    produce(CH0(p ^ 1));
    // P2: cell1  (K = [h1(t-1) 512 | h0(t) 512]); j<8 may pre-issue
    // (h1(t-1) guaranteed by own P3(t-1) CH1-wait); j>=8 issues post-wait.
    if (j < 8)
      cell_phase_reg<16, 8, true>(gbig, h1buf[p], 512, h0buf[p ^ 1], 512,
                                  wg1, b1r, c1r, h1buf[p ^ 1], row0, j0,
                                  CH0(p ^ 1), 16 * full, CH1(p), 16 * half);
    else
      cell_phase_reg<16, 8, false>(gbig, h1buf[p], 512, h0buf[p ^ 1], 512,
                                   wg1, b1r, c1r, h1buf[p ^ 1], row0, j0,
                                   CH0(p ^ 1), 16 * full, CH1(p), 16 * half);
    produce(CH1(p ^ 1));
    // P3: j<8 -> z(t) = fc(h1(t)); j>=8 -> out(t-1) = lin(z(t-1))
    if (j < 8) {
      wait1(CH1(p ^ 1), 16 * full);
      proj_partials<4>(Atp, gbufp, h1buf[p ^ 1], 512, wpj, row0);
      const int m = threadIdx.x >> 3, nb = (threadIdx.x & 7) * 4;
      const int n0 = j * 32;
      short zz[4];
#pragma unroll
      for (int u = 0; u < 4; ++u) {
        int n = nb + u;
        float v = gbufp[(0 * 64 + m) * 32 + n] + gbufp[(1 * 64 + m) * 32 + n] +
                  gbufp[(2 * 64 + m) * 32 + n] + gbufp[(3 * 64 + m) * 32 + n] +
                  fbr[u];
        zz[u] = f2bf(v);
      }
      ull zv; __builtin_memcpy(&zv, zz, 8);
      *(ull*)&zbuf[p][(size_t)(row0 + m) * 256 + n0 + nb] = zv;
      produce(CZ(p));
    } else if (t > 0) {
      // z(t-1) freshness guaranteed by this step's P1 wait (program order)
      proj_partials<2>(Atp, gbufp, zbuf[p ^ 1], 256, wpj, row0);
      const int m = threadIdx.x >> 3, nb = (threadIdx.x & 7) * 4;
      const int n0 = (j - 8) * 32;
      float4 ov;
      float* po = &ov.x;
#pragma unroll
      for (int u = 0; u < 4; ++u) {
        int n = nb + u;
        po[u] = gbufp[(0 * 64 + m) * 32 + n] + gbufp[(1 * 64 + m) * 32 + n] +
                gbufp[(2 * 64 + m) * 32 + n] + gbufp[(3 * 64 + m) * 32 + n] +
                fbr[u];
      }
      *(float4*)&outp[(size_t)(t - 1) * 262144 + (size_t)(row0 + m) * 256 + n0 + nb] = ov;
    }
  }
  // final out(127) from z(127) in zbuf[1]: z[1] rounds = prep + fc odd t = 65
  if (j >= 8) {
    wait1(CZ(1), 8 * 65);
    proj_partials<2>(Atp, gbufp, zbuf[1], 256, wpj, row0);
    const int m = threadIdx.x >> 3, nb = (threadIdx.x & 7) * 4;
    const int n0 = (j - 8) * 32;
    float4 ov;
    float* po = &ov.x;
#pragma unroll
    for (int u = 0; u < 4; ++u) {
      int n = nb + u;
      po[u] = gbufp[(0 * 64 + m) * 32 + n] + gbufp[(1 * 64 + m) * 32 + n] +
              gbufp[(2 * 64 + m) * 32 + n] + gbufp[(3 * 64 + m) * 32 + n] +
              fbr[u];
    }
    *(float4*)&outp[(size_t)127 * 262144 + (size_t)(row0 + m) * 256 + n0 + nb] = ov;
  }
#undef CZ
#undef CH0
#undef CH1
}

// ---------------------------------------------------------------------------
extern "C" void kernel_launch(void* const* d_in, const int* in_sizes, int n_in,
                              void* d_out, int out_size, void* d_ws, size_t ws_size,
                              hipStream_t stream) {
  const float* z0   = (const float*)d_in[0];
  const float* h0in = (const float*)d_in[1];
  const float* c0in = (const float*)d_in[2];
  const float* Wih0 = (const float*)d_in[3];
  const float* Whh0 = (const float*)d_in[4];
  const float* bih0 = (const float*)d_in[5];
  const float* bhh0 = (const float*)d_in[6];
  const float* Wih1 = (const float*)d_in[7];
  const float* Whh1 = (const float*)d_in[8];
  const float* bih1 = (const float*)d_in[9];
  const float* bhh1 = (const float*)d_in[10];
  const float* fcW  = (const float*)d_in[11];
  const float* fcb  = (const float*)d_in[12];
  const float* linW = (const float*)d_in[13];
  const float* linb = (const float*)d_in[14];
  float* out = (float*)d_out;

  char* ws = (char*)d_ws;
  short* wsw0  = (short*)(ws + 0);         // 3,145,728 B
  short* wsw1  = (short*)(ws + 3145728);   // 4,194,304 B
  short* fcWsw = (short*)(ws + 7340032);   //   262,144 B
  short* linWsw= (short*)(ws + 7602176);   //   131,072 B
  float* bias0 = (float*)(ws + 7733248);   //     8,192 B
  float* bias1 = (float*)(ws + 7741440);   //     8,192 B
  short* zb0   = (short*)(ws + 7749632);   //   524,288 B
  short* zb1   = (short*)(ws + 8273920);   //   524,288 B
  short* h0b0  = (short*)(ws + 8798208);   // 1,048,576 B
  short* h0b1  = (short*)(ws + 9846784);
  short* h1b0  = (short*)(ws + 10895360);
  short* h1b1  = (short*)(ws + 11943936);
  int*   flags = (int*)  (ws + 12992512);  //    33,792 B (total ~13 MB)

  prep_kernel<<<20273, 256, 0, stream>>>(z0, h0in, Wih0, Whh0, bih0, bhh0,
                                         Wih1, Whh1, bih1, bhh1, fcW, linW,
                                         wsw0, wsw1, fcWsw, linWsw, bias0, bias1,
                                         zb1, h0b0, h1b0, flags);

  decoder_persist<<<256, 512, 0, stream>>>(
      wsw0, wsw1, fcWsw, linWsw, bias0, bias1, fcb, linb, c0in,
      h0b0, h0b1, h1b0, h1b1, zb0, zb1, flags, out);
}